// Round 2
// baseline (711.647 us; speedup 1.0000x reference)
//
#include <hip/hip_runtime.h>
#include <math.h>

// B=2, C=32, H=80, W=80, D=80 fp32.
// slice (b,c,h) = contiguous [W=80][D=80] block. NSLICE = 5120, 2560/batch.
// S[b,w,v] = sum_slices X[w][:]·T[v][:];  out_slice = att_b(80x80) @ G_slice.
//
// Structure: per-WAVE pipelines (no barriers in hot loop). 8x8 lanes x 10x10
// register tile -> 200 FMA per 20 ds_read_b64; all LDS reads are 8-address
// broadcasts (conflict-free). Global->LDS chunk staging is register-prefetched
// one chunk ahead (loads in flight during compute). 512 blocks = 2/CU exact.

#define WW 80
#define DD 80
#define SLICE 6400
#define SPB 2560         // slices per batch
#define CPAD 20          // chunk row stride in floats (80B rows: 16B-aligned, 2-way banks max)

// ---------------- QK ----------------
__global__ __launch_bounds__(256, 2)
void qk2_kernel(const float* __restrict__ x, const float* __restrict__ xt,
                float* __restrict__ S) {
  __shared__ __align__(16) float lds[4][2][WW][CPAD];   // 51.2 KB
  const int tid  = threadIdx.x;
  const int wv   = tid >> 6;
  const int lane = tid & 63;
  const int r    = lane >> 3;      // 0..7
  const int c    = lane & 7;       // 0..7
  const int bi   = blockIdx.x;     // 0..511

  // block owns slices [10*bi, 10*bi+10) (never crosses a batch: 2560=256*10).
  // wave slice counts {2,3} alternating by (bi+wv)&1; prefix closed-form.
  const int ns = 2 + ((bi + wv) & 1);
  const int s0 = bi * 10 + 2 * wv + ((wv + (bi & 1)) >> 1);
  const int batch = (bi * 10) / SPB;

  float* Xc = &lds[wv][0][0][0];
  float* Tc = &lds[wv][1][0][0];

  const int row0 = lane >> 2;      // 0..15 (staging row base)
  const int c4   = lane & 3;       // float4 column within 16-wide chunk

  float acc[10][10] = {};

  float4 px[5], pt[5];
  { // prefetch (slice s0, chunk 0)
    const float* pbx = x  + (long)s0 * SLICE + c4 * 4;
    const float* pbt = xt + (long)s0 * SLICE + c4 * 4;
    #pragma unroll
    for (int t = 0; t < 5; ++t) {
      px[t] = *(const float4*)(pbx + (row0 + 16 * t) * DD);
      pt[t] = *(const float4*)(pbt + (row0 + 16 * t) * DD);
    }
  }

  for (int s = 0; s < ns; ++s) {
    for (int ch = 0; ch < 5; ++ch) {
      // stage current chunk regs -> LDS (wave-synchronous; DS is in-order)
      #pragma unroll
      for (int t = 0; t < 5; ++t) {
        *(float4*)(Xc + (row0 + 16 * t) * CPAD + c4 * 4) = px[t];
        *(float4*)(Tc + (row0 + 16 * t) * CPAD + c4 * 4) = pt[t];
      }
      // issue next chunk's global loads (in flight during compute below)
      {
        int s2 = s, ch2 = ch + 1;
        if (ch2 == 5) { ch2 = 0; s2 = s + 1; }
        if (s2 < ns) {
          const float* pbx = x  + (long)(s0 + s2) * SLICE + ch2 * 16 + c4 * 4;
          const float* pbt = xt + (long)(s0 + s2) * SLICE + ch2 * 16 + c4 * 4;
          #pragma unroll
          for (int t = 0; t < 5; ++t) {
            px[t] = *(const float4*)(pbx + (row0 + 16 * t) * DD);
            pt[t] = *(const float4*)(pbt + (row0 + 16 * t) * DD);
          }
        }
      }
      // compute: 8 x (20 ds_read_b64 + 200 FMA); all reads 8-addr broadcast
      #pragma unroll 2
      for (int kk = 0; kk < 16; kk += 2) {
        float2 a[10], bb[10];
        #pragma unroll
        for (int i = 0; i < 10; ++i)
          a[i] = *(const float2*)(Xc + (r * 10 + i) * CPAD + kk);
        #pragma unroll
        for (int j = 0; j < 10; ++j)
          bb[j] = *(const float2*)(Tc + (c * 10 + j) * CPAD + kk);
        #pragma unroll
        for (int i = 0; i < 10; ++i)
          #pragma unroll
          for (int j = 0; j < 10; ++j) {
            acc[i][j] = fmaf(a[i].x, bb[j].x, acc[i][j]);
            acc[i][j] = fmaf(a[i].y, bb[j].y, acc[i][j]);
          }
      }
    }
  }

  // 2-round block reduction in LDS (reuses chunk buffers: 12800 floats)
  float* flat = &lds[0][0][0][0];
  __syncthreads();
  if (wv & 1) {                       // waves 1,3 write
    float* reg = flat + (wv >> 1) * SLICE;
    #pragma unroll
    for (int i = 0; i < 10; ++i)
      #pragma unroll
      for (int p = 0; p < 5; ++p) {
        float2 v = { acc[i][2 * p], acc[i][2 * p + 1] };
        *(float2*)(reg + (r * 10 + i) * WW + c * 10 + 2 * p) = v;
      }
  }
  __syncthreads();
  if (!(wv & 1)) {                    // waves 0,2 accumulate
    const float* reg = flat + (wv >> 1) * SLICE;
    #pragma unroll
    for (int i = 0; i < 10; ++i)
      #pragma unroll
      for (int p = 0; p < 5; ++p) {
        float2 v = *(const float2*)(reg + (r * 10 + i) * WW + c * 10 + 2 * p);
        acc[i][2 * p]     += v.x;
        acc[i][2 * p + 1] += v.y;
      }
  }
  __syncthreads();
  if (wv == 2) {
    #pragma unroll
    for (int i = 0; i < 10; ++i)
      #pragma unroll
      for (int p = 0; p < 5; ++p) {
        float2 v = { acc[i][2 * p], acc[i][2 * p + 1] };
        *(float2*)(flat + (r * 10 + i) * WW + c * 10 + 2 * p) = v;
      }
  }
  __syncthreads();
  if (wv == 0) {
    float* Sb = S + batch * SLICE;
    #pragma unroll
    for (int i = 0; i < 10; ++i)
      #pragma unroll
      for (int p = 0; p < 5; ++p) {
        float2 v = *(const float2*)(flat + (r * 10 + i) * WW + c * 10 + 2 * p);
        atomicAdd(&Sb[(r * 10 + i) * WW + c * 10 + 2 * p],     acc[i][2 * p]     + v.x);
        atomicAdd(&Sb[(r * 10 + i) * WW + c * 10 + 2 * p + 1], acc[i][2 * p + 1] + v.y);
      }
  }
}

// ---------------- softmax over v, in place; one wave per row ----------------
__global__ void softmax_kernel(float* __restrict__ S) {
  const int rr = blockIdx.x;         // 0..159 (b*80 + w)
  const int lane = threadIdx.x;      // 0..63
  float* row = S + rr * WW;
  float v0 = (lane < WW) ? row[lane] : -INFINITY;
  float v1 = (lane + 64 < WW) ? row[lane + 64] : -INFINITY;
  float m = fmaxf(v0, v1);
  #pragma unroll
  for (int off = 32; off; off >>= 1) m = fmaxf(m, __shfl_xor(m, off));
  float e0 = (lane < WW) ? expf(v0 - m) : 0.f;
  float e1 = (lane + 64 < WW) ? expf(v1 - m) : 0.f;
  float ssum = e0 + e1;
  #pragma unroll
  for (int off = 32; off; off >>= 1) ssum += __shfl_xor(ssum, off);
  float inv = 1.f / ssum;
  if (lane < WW) row[lane] = e0 * inv;
  if (lane + 64 < WW) row[lane + 64] = e1 * inv;
}

// ---------------- PV: out_slice = att_b @ G_slice ----------------
__global__ __launch_bounds__(256, 2)
void pv2_kernel(const float* __restrict__ g, const float* __restrict__ att,
                float* __restrict__ out) {
  __shared__ __align__(16) float As[WW][84];      // 26.9 KB, shared by block
  __shared__ __align__(16) float Gc[4][16][84];   // per-wave v-chunk, 21.5 KB
  const int tid  = threadIdx.x;
  const int wv   = tid >> 6;
  const int lane = tid & 63;
  const int r    = lane >> 3;
  const int c    = lane & 7;
  const int bi   = blockIdx.x;

  const int ns = 2 + ((bi + wv) & 1);
  const int s0 = bi * 10 + 2 * wv + ((wv + (bi & 1)) >> 1);
  const int batch = (bi * 10) / SPB;

  // stage att once per block
  const float* ab = att + batch * SLICE;
  for (int f = tid; f < 1600; f += 256) {
    int row = f / 20, c4f = f - row * 20;
    *(float4*)(&As[row][c4f * 4]) = *(const float4*)(ab + row * WW + c4f * 4);
  }
  __syncthreads();

  float* Gw = &Gc[wv][0][0];
  const int vrow = lane >> 2;        // 0..15
  const int c4   = lane & 3;

  float4 pg[5];
  { // prefetch (s0, chunk 0): rows v=0..15, cols c4+4t
    const float* pb = g + (long)s0 * SLICE + vrow * DD + c4 * 4;
    #pragma unroll
    for (int t = 0; t < 5; ++t)
      pg[t] = *(const float4*)(pb + 16 * t);
  }

  for (int s = 0; s < ns; ++s) {
    float acc[10][10] = {};
    for (int ch = 0; ch < 5; ++ch) {
      #pragma unroll
      for (int t = 0; t < 5; ++t)
        *(float4*)(Gw + vrow * 84 + (c4 + 4 * t) * 4) = pg[t];
      { // prefetch next chunk
        int s2 = s, ch2 = ch + 1;
        if (ch2 == 5) { ch2 = 0; s2 = s + 1; }
        if (s2 < ns) {
          const float* pb = g + (long)(s0 + s2) * SLICE + (ch2 * 16 + vrow) * DD + c4 * 4;
          #pragma unroll
          for (int t = 0; t < 5; ++t)
            pg[t] = *(const float4*)(pb + 16 * t);
        }
      }
      const int v0 = ch * 16;
      #pragma unroll 2
      for (int kk = 0; kk < 16; kk += 2) {
        float2 a[10];
        #pragma unroll
        for (int i = 0; i < 10; ++i)
          a[i] = *(const float2*)(&As[r * 10 + i][v0 + kk]);
        float2 gA[5], gB[5];
        #pragma unroll
        for (int p = 0; p < 5; ++p) {
          gA[p] = *(const float2*)(Gw + kk * 84 + c * 10 + 2 * p);
          gB[p] = *(const float2*)(Gw + (kk + 1) * 84 + c * 10 + 2 * p);
        }
        #pragma unroll
        for (int i = 0; i < 10; ++i)
          #pragma unroll
          for (int p = 0; p < 5; ++p) {
            acc[i][2 * p]     = fmaf(a[i].x, gA[p].x, acc[i][2 * p]);
            acc[i][2 * p + 1] = fmaf(a[i].x, gA[p].y, acc[i][2 * p + 1]);
            acc[i][2 * p]     = fmaf(a[i].y, gB[p].x, acc[i][2 * p]);
            acc[i][2 * p + 1] = fmaf(a[i].y, gB[p].y, acc[i][2 * p + 1]);
          }
      }
    }
    float* po = out + (long)(s0 + s) * SLICE;
    #pragma unroll
    for (int i = 0; i < 10; ++i)
      #pragma unroll
      for (int p = 0; p < 5; ++p) {
        float2 v = { acc[i][2 * p], acc[i][2 * p + 1] };
        *(float2*)(po + (r * 10 + i) * DD + c * 10 + 2 * p) = v;
      }
  }
}

extern "C" void kernel_launch(void* const* d_in, const int* in_sizes, int n_in,
                              void* d_out, int out_size, void* d_ws, size_t ws_size,
                              hipStream_t stream) {
  const float* x_  = (const float*)d_in[0];
  const float* x_t = (const float*)d_in[1];
  const float* g_x = (const float*)d_in[2];
  float* out = (float*)d_out;
  float* S = (float*)d_ws;                    // 2*80*80 fp32 = 51.2 KB

  hipMemsetAsync(S, 0, 2 * SLICE * sizeof(float), stream);
  qk2_kernel<<<dim3(512), dim3(256), 0, stream>>>(x_, x_t, S);
  softmax_kernel<<<dim3(160), dim3(64), 0, stream>>>(S);
  pv2_kernel<<<dim3(512), dim3(256), 0, stream>>>(g_x, S, out);
}